// Round 3
// baseline (570.728 us; speedup 1.0000x reference)
//
#include <hip/hip_runtime.h>
#include <hip/hip_bf16.h>
#include <stdint.h>

typedef unsigned short u16;
typedef unsigned int   u32;

#define N_NODES 50000
#define N_EDGES 400000
#define DDIM    512
#define TSTR    40   // LDS tile row stride (u16): 32 data + 8 pad

typedef __attribute__((ext_vector_type(8))) __bf16 bf16x8;
typedef __attribute__((ext_vector_type(4))) float  f32x4;

// ---------- helpers ----------
__device__ __forceinline__ u16 f2bf(float f) {
    u32 u = __builtin_bit_cast(u32, f);
    u32 r = u + 0x7fffu + ((u >> 16) & 1u);   // RNE; inputs finite
    return (u16)(r >> 16);
}
__device__ __forceinline__ u32 pack2(float a, float b) {
    return (u32)f2bf(a) | ((u32)f2bf(b) << 16);
}

// ---------- 1. histogram of dst ----------
__global__ void hist_k(const int* __restrict__ dst, int* __restrict__ counts) {
    int e = blockIdx.x * 256 + threadIdx.x;
    if (e < N_EDGES) atomicAdd(&counts[dst[e]], 1);
}

// ---------- 2. exclusive scan (single block) ----------
__global__ __launch_bounds__(1024) void scan_k(const int* __restrict__ counts,
                                               int* __restrict__ offsets,
                                               int* __restrict__ cursor) {
    __shared__ int lds[1024];
    int t = threadIdx.x;
    int base = t * 49;
    int s = 0;
    for (int i = base; i < base + 49 && i < N_NODES; i++) s += counts[i];
    lds[t] = s;
    __syncthreads();
    int my = s;
    for (int d = 1; d < 1024; d <<= 1) {
        int v = (t >= d) ? lds[t - d] : 0;
        __syncthreads();
        lds[t] += v;
        __syncthreads();
    }
    int run = lds[t] - my;
    for (int i = base; i < base + 49 && i < N_NODES; i++) {
        offsets[i] = run;
        cursor[i]  = run;
        run += counts[i];
    }
}

// ---------- 3. fill CSR ----------
__global__ void fill_k(const int* __restrict__ src, const int* __restrict__ dst,
                       int* __restrict__ cursor, int* __restrict__ esrc) {
    int e = blockIdx.x * 256 + threadIdx.x;
    if (e < N_EDGES) {
        int d = dst[e];
        int p = atomicAdd(&cursor[d], 1);
        esrc[p] = src[e];
    }
}

// ---------- 4. prep: Wt12[n][k]=bf16(W1[k][n]+W2[k][n]), Wt2[n][k]=bf16(W2[k][n]), b12=f32(b1+b2) ----------
__global__ void prepw_k(const float* __restrict__ W1, const float* __restrict__ W2,
                        const float* __restrict__ b1, const float* __restrict__ b2,
                        u16* __restrict__ Wt12, u16* __restrict__ Wt2, float* __restrict__ b12) {
    int idx = blockIdx.x * 256 + threadIdx.x;          // 0..262143
    int n = idx >> 9, k = idx & 511;
    float w1 = W1[k * 512 + n], w2 = W2[k * 512 + n];
    Wt12[idx] = f2bf(w1 + w2);
    Wt2[idx]  = f2bf(w2);
    if (idx < 512) b12[idx] = b1[idx] + b2[idx];
}

// ---------- 5. aggregate: meanNeg[n][d] = bf16( -(1/deg) * sum x[src_e][d] ), x is f32 ----------
__global__ __launch_bounds__(256) void agg_k(const float* __restrict__ x,
                                             const int* __restrict__ offsets,
                                             const int* __restrict__ counts,
                                             const int* __restrict__ esrc,
                                             u16* __restrict__ meanNeg) {
    int nid = blockIdx.x * 4 + (threadIdx.x >> 6);
    if (nid >= N_NODES) return;
    int lane = threadIdx.x & 63;
    int off = offsets[nid], deg = counts[nid];
    float acc[8] = {0, 0, 0, 0, 0, 0, 0, 0};

    int e = 0;
    for (; e + 1 < deg; e += 2) {
        int s0 = esrc[off + e], s1 = esrc[off + e + 1];
        const float* r0 = x + (size_t)s0 * DDIM + lane * 8;
        const float* r1 = x + (size_t)s1 * DDIM + lane * 8;
        float4 a0 = ((const float4*)r0)[0], a1 = ((const float4*)r0)[1];
        float4 b0 = ((const float4*)r1)[0], b1 = ((const float4*)r1)[1];
        acc[0] += a0.x + b0.x; acc[1] += a0.y + b0.y;
        acc[2] += a0.z + b0.z; acc[3] += a0.w + b0.w;
        acc[4] += a1.x + b1.x; acc[5] += a1.y + b1.y;
        acc[6] += a1.z + b1.z; acc[7] += a1.w + b1.w;
    }
    if (e < deg) {
        int s0 = esrc[off + e];
        const float* r0 = x + (size_t)s0 * DDIM + lane * 8;
        float4 a0 = ((const float4*)r0)[0], a1 = ((const float4*)r0)[1];
        acc[0] += a0.x; acc[1] += a0.y; acc[2] += a0.z; acc[3] += a0.w;
        acc[4] += a1.x; acc[5] += a1.y; acc[6] += a1.z; acc[7] += a1.w;
    }
    float scale = (deg > 0) ? (-1.0f / (float)deg) : 0.0f;
    uint4 o;
    o.x = pack2(acc[0] * scale, acc[1] * scale);
    o.y = pack2(acc[2] * scale, acc[3] * scale);
    o.z = pack2(acc[4] * scale, acc[5] * scale);
    o.w = pack2(acc[6] * scale, acc[7] * scale);
    *(uint4*)(meanNeg + (size_t)nid * DDIM + lane * 8) = o;
}

// ---------- 6. GEMM: out = x@Wt12^T + meanNeg@Wt2^T + b12 (f32 out, masked) ----------
__global__ __launch_bounds__(256) void gemm_k(const float* __restrict__ x,
                                              const u16* __restrict__ meanNeg,
                                              const u16* __restrict__ Wt12,
                                              const u16* __restrict__ Wt2,
                                              const float* __restrict__ b12,
                                              const int* __restrict__ counts,
                                              float* __restrict__ out) {
    __shared__ u16 As[128 * TSTR];
    __shared__ u16 Bs[128 * TSTR];
    const int m0 = blockIdx.x * 128;
    const int n0 = blockIdx.y * 128;
    const int tid = threadIdx.x;
    const int lane = tid & 63;
    const int wid  = tid >> 6;
    const int wm = wid >> 1, wn = wid & 1;
    const int quad = lane >> 4, lr = lane & 15;

    f32x4 acc[4][4] = {};

    const int skoff = (lane & 3) * 8;      // k offset (elements) within 32
    const int r0 = wid * 32 + (lane >> 2); // rows r0, r0+16 staged by this thread

    int ar0 = m0 + r0;       if (ar0 >= N_NODES) ar0 = N_NODES - 1;
    int ar1 = m0 + r0 + 16;  if (ar1 >= N_NODES) ar1 = N_NODES - 1;
    const int br0 = n0 + r0, br1 = n0 + r0 + 16;

    for (int pass = 0; pass < 2; pass++) {
        const u16* __restrict__ B = pass ? Wt2 : Wt12;
        for (int k0 = 0; k0 < 512; k0 += 32) {
            uint4 va0, va1;
            if (pass == 0) {
                // A = x (f32) -> cvt to bf16 in regs
                const float* p0 = x + (size_t)ar0 * DDIM + k0 + skoff;
                const float* p1 = x + (size_t)ar1 * DDIM + k0 + skoff;
                float4 f00 = ((const float4*)p0)[0], f01 = ((const float4*)p0)[1];
                float4 f10 = ((const float4*)p1)[0], f11 = ((const float4*)p1)[1];
                va0.x = pack2(f00.x, f00.y); va0.y = pack2(f00.z, f00.w);
                va0.z = pack2(f01.x, f01.y); va0.w = pack2(f01.z, f01.w);
                va1.x = pack2(f10.x, f10.y); va1.y = pack2(f10.z, f10.w);
                va1.z = pack2(f11.x, f11.y); va1.w = pack2(f11.z, f11.w);
            } else {
                va0 = *(const uint4*)(meanNeg + (size_t)ar0 * DDIM + k0 + skoff);
                va1 = *(const uint4*)(meanNeg + (size_t)ar1 * DDIM + k0 + skoff);
            }
            uint4 vb0 = *(const uint4*)(B + (size_t)br0 * DDIM + k0 + skoff);
            uint4 vb1 = *(const uint4*)(B + (size_t)br1 * DDIM + k0 + skoff);
            __syncthreads();   // prior iteration's LDS reads complete
            *(uint4*)&As[r0 * TSTR + skoff]        = va0;
            *(uint4*)&As[(r0 + 16) * TSTR + skoff] = va1;
            *(uint4*)&Bs[r0 * TSTR + skoff]        = vb0;
            *(uint4*)&Bs[(r0 + 16) * TSTR + skoff] = vb1;
            __syncthreads();   // staging visible
            bf16x8 af[4], bfr[4];
            #pragma unroll
            for (int i = 0; i < 4; i++)
                af[i] = *(const bf16x8*)&As[(wm * 64 + i * 16 + lr) * TSTR + quad * 8];
            #pragma unroll
            for (int j = 0; j < 4; j++)
                bfr[j] = *(const bf16x8*)&Bs[(wn * 64 + j * 16 + lr) * TSTR + quad * 8];
            #pragma unroll
            for (int i = 0; i < 4; i++)
                #pragma unroll
                for (int j = 0; j < 4; j++)
                    acc[i][j] = __builtin_amdgcn_mfma_f32_16x16x32_bf16(af[i], bfr[j], acc[i][j], 0, 0, 0);
        }
    }

    // epilogue: C/D layout col=lane&15, row=quad*4+r ; f32 output
    #pragma unroll
    for (int i = 0; i < 4; i++) {
        #pragma unroll
        for (int r = 0; r < 4; r++) {
            int grow = m0 + wm * 64 + i * 16 + quad * 4 + r;
            if (grow >= N_NODES) continue;
            int cnt = counts[grow];
            #pragma unroll
            for (int j = 0; j < 4; j++) {
                int gcol = n0 + wn * 64 + j * 16 + lr;
                float v;
                if (cnt > 0) v = acc[i][j][r] + b12[gcol];
                else         v = x[(size_t)grow * DDIM + gcol];   // exact passthrough
                out[(size_t)grow * DDIM + gcol] = v;
            }
        }
    }
}

// ---------- launch ----------
extern "C" void kernel_launch(void* const* d_in, const int* in_sizes, int n_in,
                              void* d_out, int out_size, void* d_ws, size_t ws_size,
                              hipStream_t stream) {
    const float* x  = (const float*)d_in[0];
    const int* src  = (const int*)d_in[1];
    const int* dst  = (const int*)d_in[2];
    const float* W1 = (const float*)d_in[3];
    const float* b1 = (const float*)d_in[4];
    const float* W2 = (const float*)d_in[5];
    const float* b2 = (const float*)d_in[6];
    float* out = (float*)d_out;

    char* ws = (char*)d_ws;
    size_t o = 0;
    auto alloc = [&](size_t bytes) { char* p = ws + o; o += (bytes + 255) & ~(size_t)255; return p; };
    int* counts   = (int*)alloc((size_t)N_NODES * 4);
    int* offsets  = (int*)alloc((size_t)N_NODES * 4);
    int* cursor   = (int*)alloc((size_t)N_NODES * 4);
    int* esrc     = (int*)alloc((size_t)N_EDGES * 4);
    u16* Wt12     = (u16*)alloc((size_t)512 * 512 * 2);
    u16* Wt2      = (u16*)alloc((size_t)512 * 512 * 2);
    float* b12    = (float*)alloc((size_t)512 * 4);
    u16* meanNeg  = (u16*)alloc((size_t)N_NODES * DDIM * 2);   // ~54.4 MB total ws
    (void)ws_size; (void)n_in; (void)in_sizes; (void)out_size;

    hipMemsetAsync(counts, 0, (size_t)N_NODES * 4, stream);
    hist_k<<<(N_EDGES + 255) / 256, 256, 0, stream>>>(dst, counts);
    scan_k<<<1, 1024, 0, stream>>>(counts, offsets, cursor);
    fill_k<<<(N_EDGES + 255) / 256, 256, 0, stream>>>(src, dst, cursor, esrc);
    prepw_k<<<(512 * 512) / 256, 256, 0, stream>>>(W1, W2, b1, b2, Wt12, Wt2, b12);
    agg_k<<<(N_NODES + 3) / 4, 256, 0, stream>>>(x, offsets, counts, esrc, meanNeg);
    gemm_k<<<dim3((N_NODES + 127) / 128, DDIM / 128), 256, 0, stream>>>(
        x, meanNeg, Wt12, Wt2, b12, counts, out);
}

// Round 4
// 433.883 us; speedup vs baseline: 1.3154x; 1.3154x over previous
//
#include <hip/hip_runtime.h>
#include <hip/hip_bf16.h>
#include <stdint.h>

typedef unsigned short u16;
typedef unsigned int   u32;

#define N_NODES 50000
#define N_EDGES 400000
#define DDIM    512

typedef __attribute__((ext_vector_type(8))) __bf16 bf16x8;
typedef __attribute__((ext_vector_type(4))) float  f32x4;

// ---------- helpers ----------
__device__ __forceinline__ float bflo(u32 d) { return __builtin_bit_cast(float, d << 16); }
__device__ __forceinline__ float bfhi(u32 d) { return __builtin_bit_cast(float, d & 0xffff0000u); }
__device__ __forceinline__ u16 f2bf(float f) {
    u32 u = __builtin_bit_cast(u32, f);
    u32 r = u + 0x7fffu + ((u >> 16) & 1u);   // RNE; inputs finite
    return (u16)(r >> 16);
}
__device__ __forceinline__ u32 pack2(float a, float b) {
    return (u32)f2bf(a) | ((u32)f2bf(b) << 16);
}
__device__ __forceinline__ void gload_lds16(const void* g, void* l) {
    __builtin_amdgcn_global_load_lds(
        (const __attribute__((address_space(1))) void*)g,
        (__attribute__((address_space(3))) void*)l, 16, 0, 0);
}

// ---------- 0. x (f32) -> xb (bf16) ----------
__global__ void cvt_k(const float* __restrict__ x, u16* __restrict__ xb) {
    int i = blockIdx.x * 256 + threadIdx.x;          // 8 elements per thread
    const float4* p = (const float4*)(x + (size_t)i * 8);
    float4 a = p[0], b = p[1];
    uint4 o;
    o.x = pack2(a.x, a.y); o.y = pack2(a.z, a.w);
    o.z = pack2(b.x, b.y); o.w = pack2(b.z, b.w);
    ((uint4*)xb)[i] = o;
}

// ---------- 1. histogram of dst ----------
__global__ void hist_k(const int* __restrict__ dst, int* __restrict__ counts) {
    int e = blockIdx.x * 256 + threadIdx.x;
    if (e < N_EDGES) atomicAdd(&counts[dst[e]], 1);
}

// ---------- 2. three-phase exclusive scan (49 chunks of 1024) ----------
#define NCHUNK 49
__global__ __launch_bounds__(1024) void scanA_k(const int* __restrict__ counts, int* __restrict__ csum) {
    __shared__ int ws[16];
    int t = threadIdx.x, b = blockIdx.x;
    int i = b * 1024 + t;
    int v = (i < N_NODES) ? counts[i] : 0;
    for (int d = 32; d; d >>= 1) v += __shfl_down(v, d);
    if ((t & 63) == 0) ws[t >> 6] = v;
    __syncthreads();
    if (t < 16) {
        int s = ws[t];
        for (int d = 8; d; d >>= 1) s += __shfl_down(s, d);
        if (t == 0) csum[b] = s;
    }
}
__global__ void scanB_k(int* __restrict__ csum) {   // 64 threads, exclusive in-place
    int t = threadIdx.x;
    int v = (t < NCHUNK) ? csum[t] : 0;
    int s = v;
    for (int d = 1; d < 64; d <<= 1) { int u = __shfl_up(s, d); if (t >= d) s += u; }
    if (t < NCHUNK) csum[t] = s - v;
}
__global__ __launch_bounds__(1024) void scanC_k(const int* __restrict__ counts, const int* __restrict__ csum,
                                                int* __restrict__ offsets, int* __restrict__ cursor) {
    __shared__ int wsum[16];
    int t = threadIdx.x, b = blockIdx.x;
    int i = b * 1024 + t;
    int lane = t & 63, w = t >> 6;
    int v = (i < N_NODES) ? counts[i] : 0;
    int s = v;
    for (int d = 1; d < 64; d <<= 1) { int u = __shfl_up(s, d); if (lane >= d) s += u; }
    if (lane == 63) wsum[w] = s;
    __syncthreads();
    if (t < 16) {
        int ww = wsum[t], ss = ww;
        for (int d = 1; d < 16; d <<= 1) { int u = __shfl_up(ss, d); if (t >= d) ss += u; }
        wsum[t] = ss - ww;
    }
    __syncthreads();
    int excl = (s - v) + wsum[w] + csum[b];
    if (i < N_NODES) { offsets[i] = excl; cursor[i] = excl; }
}

// ---------- 3. fill CSR ----------
__global__ void fill_k(const int* __restrict__ src, const int* __restrict__ dst,
                       int* __restrict__ cursor, int* __restrict__ esrc) {
    int e = blockIdx.x * 256 + threadIdx.x;
    if (e < N_EDGES) {
        int d = dst[e];
        int p = atomicAdd(&cursor[d], 1);
        esrc[p] = src[e];
    }
}

// ---------- 4. prep weights (coalesced reads, scattered writes) ----------
__global__ void prepw_k(const float* __restrict__ W1, const float* __restrict__ W2,
                        const float* __restrict__ b1, const float* __restrict__ b2,
                        u16* __restrict__ Wt12, u16* __restrict__ Wt2, float* __restrict__ b12) {
    int idx = blockIdx.x * 256 + threadIdx.x;          // = k*512 + n
    int k = idx >> 9, n = idx & 511;
    float w1 = W1[idx], w2 = W2[idx];
    Wt12[n * 512 + k] = f2bf(w1 + w2);
    Wt2[n * 512 + k]  = f2bf(w2);
    if (idx < 512) b12[idx] = b1[idx] + b2[idx];
}

// ---------- 5. aggregate from bf16 xb: meanNeg = bf16(-mean) ----------
__device__ __forceinline__ void addrow(float* acc, uint4 v) {
    acc[0] += bflo(v.x); acc[1] += bfhi(v.x);
    acc[2] += bflo(v.y); acc[3] += bfhi(v.y);
    acc[4] += bflo(v.z); acc[5] += bfhi(v.z);
    acc[6] += bflo(v.w); acc[7] += bfhi(v.w);
}
__global__ __launch_bounds__(256) void agg_k(const u16* __restrict__ xb,
                                             const int* __restrict__ offsets,
                                             const int* __restrict__ counts,
                                             const int* __restrict__ esrc,
                                             u16* __restrict__ meanNeg) {
    int nid = blockIdx.x * 4 + (threadIdx.x >> 6);
    if (nid >= N_NODES) return;
    int lane = threadIdx.x & 63;
    int off = offsets[nid], deg = counts[nid];
    float acc[8] = {0, 0, 0, 0, 0, 0, 0, 0};
    int e = 0;
    for (; e + 3 < deg; e += 4) {
        int s0 = esrc[off + e], s1 = esrc[off + e + 1];
        int s2 = esrc[off + e + 2], s3 = esrc[off + e + 3];
        uint4 v0 = *(const uint4*)(xb + (size_t)s0 * DDIM + lane * 8);
        uint4 v1 = *(const uint4*)(xb + (size_t)s1 * DDIM + lane * 8);
        uint4 v2 = *(const uint4*)(xb + (size_t)s2 * DDIM + lane * 8);
        uint4 v3 = *(const uint4*)(xb + (size_t)s3 * DDIM + lane * 8);
        addrow(acc, v0); addrow(acc, v1); addrow(acc, v2); addrow(acc, v3);
    }
    for (; e < deg; e++) {
        int s0 = esrc[off + e];
        addrow(acc, *(const uint4*)(xb + (size_t)s0 * DDIM + lane * 8));
    }
    float scale = (deg > 0) ? (-1.0f / (float)deg) : 0.0f;
    uint4 o;
    o.x = pack2(acc[0] * scale, acc[1] * scale);
    o.y = pack2(acc[2] * scale, acc[3] * scale);
    o.z = pack2(acc[4] * scale, acc[5] * scale);
    o.w = pack2(acc[6] * scale, acc[7] * scale);
    *(uint4*)(meanNeg + (size_t)nid * DDIM + lane * 8) = o;
}

// ---------- 6. GEMM: out = xb@Wt12^T + meanNeg@Wt2^T + b12 (f32 out, masked) ----------
// m97 pattern: global_load_lds width=16, unpadded 32-wide LDS rows, 2 barriers/k-iter.
__global__ __launch_bounds__(256) void gemm_k(const u16* __restrict__ xb,
                                              const float* __restrict__ x,
                                              const u16* __restrict__ meanNeg,
                                              const u16* __restrict__ Wt12,
                                              const u16* __restrict__ Wt2,
                                              const float* __restrict__ b12,
                                              const int* __restrict__ counts,
                                              float* __restrict__ out) {
    __shared__ u16 As[128 * 32];
    __shared__ u16 Bs[128 * 32];
    const int m0 = blockIdx.x * 128;
    const int n0 = blockIdx.y * 128;
    const int tid = threadIdx.x;
    const int lane = tid & 63;
    const int wid  = tid >> 6;
    const int wm = wid >> 1, wn = wid & 1;
    const int quad = lane >> 4, lr = lane & 15;

    f32x4 acc[4][4] = {};

    const int skoff = (lane & 3) * 8;      // u16 elements within 32-wide k-tile
    const int srsub = lane >> 2;
    int arow[2], brow[2];
    #pragma unroll
    for (int t = 0; t < 2; t++) {
        int r = wid * 32 + t * 16 + srsub;
        int ar = m0 + r; if (ar >= N_NODES) ar = N_NODES - 1;
        arow[t] = ar;
        brow[t] = n0 + r;
    }

    for (int pass = 0; pass < 2; pass++) {
        const u16* __restrict__ A = pass ? meanNeg : xb;
        const u16* __restrict__ B = pass ? Wt2 : Wt12;
        for (int k0 = 0; k0 < 512; k0 += 32) {
            #pragma unroll
            for (int t = 0; t < 2; t++) {
                int rblk = wid * 32 + t * 16;
                gload_lds16(A + (size_t)arow[t] * DDIM + k0 + skoff, &As[rblk * 32]);
                gload_lds16(B + (size_t)brow[t] * DDIM + k0 + skoff, &Bs[rblk * 32]);
            }
            __syncthreads();
            bf16x8 af[4], bfr[4];
            #pragma unroll
            for (int i = 0; i < 4; i++)
                af[i] = *(const bf16x8*)&As[(wm * 64 + i * 16 + lr) * 32 + quad * 8];
            #pragma unroll
            for (int j = 0; j < 4; j++)
                bfr[j] = *(const bf16x8*)&Bs[(wn * 64 + j * 16 + lr) * 32 + quad * 8];
            #pragma unroll
            for (int i = 0; i < 4; i++)
                #pragma unroll
                for (int j = 0; j < 4; j++)
                    acc[i][j] = __builtin_amdgcn_mfma_f32_16x16x32_bf16(af[i], bfr[j], acc[i][j], 0, 0, 0);
            __syncthreads();
        }
    }

    // epilogue: C/D layout col=lane&15, row=quad*4+r ; f32 output
    #pragma unroll
    for (int i = 0; i < 4; i++) {
        #pragma unroll
        for (int r = 0; r < 4; r++) {
            int grow = m0 + wm * 64 + i * 16 + quad * 4 + r;
            if (grow >= N_NODES) continue;
            int cnt = counts[grow];
            #pragma unroll
            for (int j = 0; j < 4; j++) {
                int gcol = n0 + wn * 64 + j * 16 + lr;
                float v;
                if (cnt > 0) v = acc[i][j][r] + b12[gcol];
                else         v = x[(size_t)grow * DDIM + gcol];   // exact passthrough
                out[(size_t)grow * DDIM + gcol] = v;
            }
        }
    }
}

// ---------- launch ----------
extern "C" void kernel_launch(void* const* d_in, const int* in_sizes, int n_in,
                              void* d_out, int out_size, void* d_ws, size_t ws_size,
                              hipStream_t stream) {
    const float* x  = (const float*)d_in[0];
    const int* src  = (const int*)d_in[1];
    const int* dst  = (const int*)d_in[2];
    const float* W1 = (const float*)d_in[3];
    const float* b1 = (const float*)d_in[4];
    const float* W2 = (const float*)d_in[5];
    const float* b2 = (const float*)d_in[6];
    float* out = (float*)d_out;

    char* ws = (char*)d_ws;
    size_t o = 0;
    auto alloc = [&](size_t bytes) { char* p = ws + o; o += (bytes + 255) & ~(size_t)255; return p; };
    int* counts   = (int*)alloc((size_t)N_NODES * 4);
    int* offsets  = (int*)alloc((size_t)N_NODES * 4);
    int* cursor   = (int*)alloc((size_t)N_NODES * 4);
    int* csum     = (int*)alloc((size_t)NCHUNK * 4);
    int* esrc     = (int*)alloc((size_t)N_EDGES * 4);
    u16* Wt12     = (u16*)alloc((size_t)512 * 512 * 2);
    u16* Wt2      = (u16*)alloc((size_t)512 * 512 * 2);
    float* b12    = (float*)alloc((size_t)512 * 4);
    u16* xb       = (u16*)alloc((size_t)N_NODES * DDIM * 2);
    u16* meanNeg  = (u16*)alloc((size_t)N_NODES * DDIM * 2);   // ~106 MB total ws
    (void)ws_size; (void)n_in; (void)in_sizes; (void)out_size;

    hipMemsetAsync(counts, 0, (size_t)N_NODES * 4, stream);
    cvt_k<<<(N_NODES * DDIM / 8) / 256, 256, 0, stream>>>(x, xb);
    hist_k<<<(N_EDGES + 255) / 256, 256, 0, stream>>>(dst, counts);
    scanA_k<<<NCHUNK, 1024, 0, stream>>>(counts, csum);
    scanB_k<<<1, 64, 0, stream>>>(csum);
    scanC_k<<<NCHUNK, 1024, 0, stream>>>(counts, csum, offsets, cursor);
    fill_k<<<(N_EDGES + 255) / 256, 256, 0, stream>>>(src, dst, cursor, esrc);
    prepw_k<<<(512 * 512) / 256, 256, 0, stream>>>(W1, W2, b1, b2, Wt12, Wt2, b12);
    agg_k<<<(N_NODES + 3) / 4, 256, 0, stream>>>(xb, offsets, counts, esrc, meanNeg);
    gemm_k<<<dim3((N_NODES + 127) / 128, DDIM / 128), 256, 0, stream>>>(
        xb, x, meanNeg, Wt12, Wt2, b12, counts, out);
}